// Round 20
// baseline (154.000 us; speedup 1.0000x reference)
//
#include <hip/hip_runtime.h>
#include <hip/hip_bf16.h>

#define NF 128
#define NC 10
#define NG 64
#define NBLK 2048     // sort blocks (8 per CU)
#define SBT 256       // sort block threads
#define NBUKMAX 400   // max buckets (n <= 102400)
#define GPAD 16       // ints per gcnt slot (64B line)
#define CAP 8192      // per-bucket capacity (mean 4092, sigma ~64)
#define RW 16         // ushorts/row (32B). half h (uint4): pk(f,f),pk(f,f),pk(f,0),f32 aux
#define SCSR 2112     // staged csr ints per gather block (expected ~512)
#define KUNR 4        // unroll depth: CH=782 <= 4*256

static inline int cdiv(int a, int b) { return (a + b - 1) / b; }

__device__ __forceinline__ float bf_lo(unsigned u) { return __uint_as_float(u << 16); }
__device__ __forceinline__ float bf_hi(unsigned u) { return __uint_as_float(u & 0xFFFF0000u); }
__device__ __forceinline__ unsigned pk_bf16(float a, float b) {
    unsigned ua = __float_as_uint(a), ub = __float_as_uint(b);
    ua = (ua + 0x7FFFu + ((ua >> 16) & 1u)) >> 16;
    ub = (ub + 0x7FFFu + ((ub >> 16) & 1u)) >> 16;
    return ua | (ub << 16);
}

// plain-add accumulate of one half-row (5 feats + aux)
#define ACC5(x4)                                    \
    a0 += bf_lo((x4).x); a1 += bf_hi((x4).x);       \
    a2 += bf_lo((x4).y); a3 += bf_hi((x4).y);       \
    a4 += bf_lo((x4).z); ds += __uint_as_float((x4).w);

// FMA accumulate scaled by the row's own aux
#define ACCF(x4) {                                  \
    float w_ = __uint_as_float((x4).w);             \
    a0 = fmaf(w_, bf_lo((x4).x), a0);               \
    a1 = fmaf(w_, bf_hi((x4).x), a1);               \
    a2 = fmaf(w_, bf_lo((x4).y), a2);               \
    a3 = fmaf(w_, bf_hi((x4).y), a3);               \
    a4 = fmaf(w_, bf_lo((x4).z), a4); }

// Fine-grained bucket sort: 2048 small blocks (8/CU) so reservation latency
// of one block hides under histogram/scatter of co-resident blocks.
// Register-batched loads (4-deep). Blocks 1..5 compute W12 slices; blk 6 c12.
__global__ __launch_bounds__(SBT) void k_sort(const int* __restrict__ row,
                                              const int* __restrict__ col,
                                              int* __restrict__ gcnt,
                                              int* __restrict__ packed2,
                                              const float* __restrict__ W1,
                                              const float* __restrict__ b1,
                                              const float* __restrict__ W2,
                                              float* __restrict__ W12,
                                              float* __restrict__ c12,
                                              int E, int CH, int nbuk) {
    __shared__ int h[NBUKMAX];
    __shared__ int hb[NBUKMAX];
    int blk = blockIdx.x, tid = threadIdx.x;
    int e0 = blk * CH;
    int ne = min(E - e0, CH);

    // batched loads: all independent, in flight together
    int cr[KUNR], rr[KUNR];
#pragma unroll
    for (int k = 0; k < KUNR; ++k) {
        int i = tid + k * SBT;
        if (i < ne) { cr[k] = col[e0 + i]; rr[k] = row[e0 + i]; }
        else { cr[k] = -1; rr[k] = 0; }
    }

    // W12 = W1@W2 spread across blocks 1..5 (one dot per thread); c12 in blk 6
    if (blk >= 1 && blk <= 5) {
        int idx = (blk - 1) * SBT + tid;
        if (idx < NF * NC) {
            int a = idx / NC, c = idx % NC;
            float s = 0.f;
            for (int m = 0; m < NF; ++m) s += W1[a * NF + m] * W2[m * NC + c];
            W12[idx] = s;
        }
    }
    if (blk == 6 && tid < NC) {
        float s = 0.f;
        for (int m = 0; m < NF; ++m) s += b1[m] * W2[m * NC + tid];
        c12[tid] = s;
    }

    for (int i = tid; i < nbuk; i += SBT) h[i] = 0;
    __syncthreads();
#pragma unroll
    for (int k = 0; k < KUNR; ++k)
        if (cr[k] >= 0) atomicAdd(&h[cr[k] >> 8], 1);
    for (int i = tid + KUNR * SBT; i < ne; i += SBT)   // defensive tail
        atomicAdd(&h[col[e0 + i] >> 8], 1);
    __syncthreads();
    for (int i = tid; i < nbuk; i += SBT) {
        int c = h[i];
        hb[i] = c ? atomicAdd(&gcnt[(size_t)i * GPAD], c) : 0;
        h[i] = 0;
    }
    __syncthreads();
#pragma unroll
    for (int k = 0; k < KUNR; ++k) {
        if (cr[k] >= 0) {
            int c = cr[k];
            int b = c >> 8;
            int t = hb[b] + atomicAdd(&h[b], 1);
            if (t < CAP)
                packed2[(size_t)b * CAP + t] = rr[k] | ((c & 255) << 17);
        }
    }
    for (int i = tid + KUNR * SBT; i < ne; i += SBT) { // defensive tail
        int c = col[e0 + i];
        int b = c >> 8;
        int t = hb[b] + atomicAdd(&h[b], 1);
        if (t < CAP)
            packed2[(size_t)b * CAP + t] = row[e0 + i] | ((c & 255) << 17);
    }
}

// Dense GEMM, fully coalesced: 8 threads/row (seg = lane&7), lane-adjacent
// float4 loads. W12 LOADED from global (computed once by k_sort blks 1..6).
// Gs[node] = X@W12 + c12 (unscaled bf16, aux slots = 0, filled by k_p3).
__global__ __launch_bounds__(256) void k_gemm(const float* __restrict__ X,
                                              const float* __restrict__ W12,
                                              const float* __restrict__ c12,
                                              unsigned short* __restrict__ Gs,
                                              int n) {
    __shared__ float Wp[NF][13];   // 13-pad: seg-stride 52 -> distinct banks
    __shared__ float c12s[NC];
    int tid = threadIdx.x;
    for (int idx = tid; idx < NF * NC; idx += 256)
        Wp[idx / NC][idx % NC] = W12[idx];
    if (tid < NC) c12s[tid] = c12[tid];
    __syncthreads();

    int r = tid >> 3, seg = tid & 7;
    int gn = blockIdx.x * 32 + r;
    if (gn >= n) return;
    const float4* xb = reinterpret_cast<const float4*>(X + (size_t)gn * NF);
    float4 x0 = xb[0 * 8 + seg];
    float4 x1 = xb[1 * 8 + seg];
    float4 x2 = xb[2 * 8 + seg];
    float4 x3 = xb[3 * 8 + seg];

    float acc[NC];
#pragma unroll
    for (int c = 0; c < NC; ++c) acc[c] = 0.f;
    const float4 xs[4] = {x0, x1, x2, x3};
#pragma unroll
    for (int c = 0; c < 4; ++c) {
        float xv[4] = {xs[c].x, xs[c].y, xs[c].z, xs[c].w};
#pragma unroll
        for (int j = 0; j < 4; ++j) {
            int k = c * 32 + seg * 4 + j;
            float x = xv[j];
#pragma unroll
            for (int f = 0; f < NC; ++f) acc[f] = fmaf(x, Wp[k][f], acc[f]);
        }
    }
#pragma unroll
    for (int m = 1; m <= 4; m <<= 1) {
#pragma unroll
        for (int c = 0; c < NC; ++c) acc[c] += __shfl_xor(acc[c], m, 8);
    }
    if (seg < 2) {
        float v[NC];
#pragma unroll
        for (int c = 0; c < NC; ++c) v[c] = acc[c] + c12s[c];
        uint4* pw = (uint4*)(Gs + (size_t)gn * RW);
        if (seg == 0)
            pw[0] = make_uint4(pk_bf16(v[0], v[1]), pk_bf16(v[2], v[3]),
                               pk_bf16(v[4], 0.f), 0u);
        else
            pw[1] = make_uint4(pk_bf16(v[5], v[6]), pk_bf16(v[7], v[8]),
                               pk_bf16(v[9], 0.f), 0u);
    }
}

// P3 (r8 proven form, 512 threads): stage segment in LDS, count, scan,
// write csr IN PLACE over packed2; emits degE/offset/dis + Gs aux words.
__global__ __launch_bounds__(512) void k_p3(int* __restrict__ packed2,
                                            const int* __restrict__ gcnt,
                                            int* __restrict__ degE,
                                            int* __restrict__ offset,
                                            float* __restrict__ dis,
                                            unsigned int* __restrict__ Gu,
                                            int n, int nbuk) {
    __shared__ int cnt[256], inc[256], cnt2[256];
    __shared__ int sp[CAP];
    int b = blockIdx.x, tid = threadIdx.x;
    size_t bs = (size_t)b * CAP;
    int seg = min(gcnt[(size_t)b * GPAD], CAP);
    if (tid < 256) { cnt[tid] = 0; cnt2[tid] = 0; }
    for (int pos = tid; pos < seg; pos += 512) sp[pos] = packed2[bs + pos];
    __syncthreads();
    for (int pos = tid; pos < seg; pos += 512)
        atomicAdd(&cnt[(sp[pos] >> 17) & 255], 1);
    __syncthreads();
    if (tid < 256) inc[tid] = cnt[tid];
    __syncthreads();
    for (int s = 1; s < 256; s <<= 1) {
        int x = 0;
        if (tid < 256 && tid >= s) x = inc[tid - s];
        __syncthreads();
        if (tid < 256) inc[tid] += x;
        __syncthreads();
    }
    int node = b * 256 + tid;
    if (tid < 256 && node < n) {
        int d = cnt[tid];
        degE[node] = d;
        offset[node] = (int)bs + inc[tid] - d;
        float dv = rsqrtf((float)(d + 1));
        dis[node] = dv;
        unsigned ud = __float_as_uint(dv);
        Gu[(size_t)node * 8 + 3] = ud;   // half0 aux
        Gu[(size_t)node * 8 + 7] = ud;   // half1 aux
    }
    __syncthreads();
    for (int pos = tid; pos < seg; pos += 512) {
        int v = sp[pos];
        int l = (v >> 17) & 255;
        int t = atomicAdd(&cnt2[l], 1);
        packed2[bs + (inc[l] - cnt[l]) + t] = v & 0x1FFFF;
    }
}

// layer-1 gather: 8 lanes/node (4 nbr-groups x 2 halves), csr staged in LDS.
// FMA-scaled by each row's aux (=dis[r]); S1 = dis_c^2 * acc, aux = dis_c.
__global__ __launch_bounds__(256) void k_gather0(const unsigned short* __restrict__ Gs,
        const int* __restrict__ csr, const int* __restrict__ offset,
        const int* __restrict__ degE, const float* __restrict__ dis,
        unsigned short* __restrict__ S1, int n) {
    __shared__ int scsr[SCSR];
    int tid = threadIdx.x;
    int g0 = blockIdx.x * 32;
    int gL = min(g0 + 31, n - 1);
    int o0 = offset[g0];
    int total = offset[gL] + degE[gL] - o0;
    bool st = (total <= SCSR);
    if (st)
        for (int i = tid; i < total; i += 256) scsr[i] = csr[o0 + i];
    __syncthreads();

    int g = g0 + (tid >> 3);
    int l = tid & 7, grp = l >> 1, half = l & 1;
    if (g >= n) return;
    int o = offset[g], d = degE[g];
    int ol = o - o0;
    float dc = dis[g];
    const uint4* base = (const uint4*)Gs;
    float a0=0,a1=0,a2=0,a3=0,a4=0;
    if (grp == 0) { uint4 x = base[(size_t)g * 2 + half]; ACCF(x); }
    int j = grp;
    if (st) {
        while (j + 12 < d) {
            int r0 = scsr[ol + j], r1 = scsr[ol + j + 4];
            int r2 = scsr[ol + j + 8], r3 = scsr[ol + j + 12];
            uint4 x0 = base[(size_t)r0 * 2 + half];
            uint4 x1 = base[(size_t)r1 * 2 + half];
            uint4 x2 = base[(size_t)r2 * 2 + half];
            uint4 x3 = base[(size_t)r3 * 2 + half];
            ACCF(x0); ACCF(x1); ACCF(x2); ACCF(x3);
            j += 16;
        }
        for (; j < d; j += 4) {
            uint4 x = base[(size_t)scsr[ol + j] * 2 + half];
            ACCF(x);
        }
    } else {
        for (; j < d; j += 4) {
            uint4 x = base[(size_t)csr[o + j] * 2 + half];
            ACCF(x);
        }
    }
#pragma unroll
    for (int m = 2; m <= 4; m <<= 1) {
        a0 += __shfl_xor(a0, m, 8); a1 += __shfl_xor(a1, m, 8);
        a2 += __shfl_xor(a2, m, 8); a3 += __shfl_xor(a3, m, 8);
        a4 += __shfl_xor(a4, m, 8);
    }
    if (l < 2) {
        float s = dc * dc;
        uint4* pw = (uint4*)(S1 + (size_t)g * RW);
        pw[half] = make_uint4(pk_bf16(a0 * s, a1 * s), pk_bf16(a2 * s, a3 * s),
                              pk_bf16(a4 * s, 0.f), __float_as_uint(dc));
    }
}

// layer-2 gather + bias + fused mean-pool; csr staged in LDS. Rows pre-scaled.
__global__ __launch_bounds__(256) void k_gather_pool(const unsigned short* __restrict__ S1,
        const int* __restrict__ csr, const int* __restrict__ offset,
        const int* __restrict__ degE, const float* __restrict__ dis,
        const float* __restrict__ b2, const int* __restrict__ batch,
        float* __restrict__ psum, float* __restrict__ cnt, int n) {
    __shared__ float ps[NG * NC];
    __shared__ float lc[NG];
    __shared__ float b2s[NC];
    __shared__ int scsr[SCSR];
    int tid = threadIdx.x;
    for (int idx = tid; idx < NG * NC; idx += 256) ps[idx] = 0.f;
    if (tid < NG) lc[tid] = 0.f;
    if (tid < NC) b2s[tid] = b2[tid];

    int g0 = blockIdx.x * 32;
    int gL = min(g0 + 31, n - 1);
    int o0 = offset[g0];
    int total = offset[gL] + degE[gL] - o0;
    bool st = (total <= SCSR);
    if (st)
        for (int i = tid; i < total; i += 256) scsr[i] = csr[o0 + i];
    __syncthreads();

    int g = g0 + (tid >> 3);
    int l = tid & 7, grp = l >> 1, half = l & 1;
    if (g < n) {
        int o = offset[g], d = degE[g];
        int ol = o - o0;
        float dc = dis[g];
        const uint4* base = (const uint4*)S1;
        float a0=0,a1=0,a2=0,a3=0,a4=0, ds=0;
        if (grp == 0) { uint4 x = base[(size_t)g * 2 + half]; ACC5(x); }
        int j = grp;
        if (st) {
            while (j + 12 < d) {
                int r0 = scsr[ol + j], r1 = scsr[ol + j + 4];
                int r2 = scsr[ol + j + 8], r3 = scsr[ol + j + 12];
                uint4 x0 = base[(size_t)r0 * 2 + half];
                uint4 x1 = base[(size_t)r1 * 2 + half];
                uint4 x2 = base[(size_t)r2 * 2 + half];
                uint4 x3 = base[(size_t)r3 * 2 + half];
                ACC5(x0); ACC5(x1); ACC5(x2); ACC5(x3);
                j += 16;
            }
            for (; j < d; j += 4) {
                uint4 x = base[(size_t)scsr[ol + j] * 2 + half];
                ACC5(x);
            }
        } else {
            for (; j < d; j += 4) {
                uint4 x = base[(size_t)csr[o + j] * 2 + half];
                ACC5(x);
            }
        }
#pragma unroll
        for (int m = 2; m <= 4; m <<= 1) {
            a0 += __shfl_xor(a0, m, 8); a1 += __shfl_xor(a1, m, 8);
            a2 += __shfl_xor(a2, m, 8); a3 += __shfl_xor(a3, m, 8);
            a4 += __shfl_xor(a4, m, 8); ds += __shfl_xor(ds, m, 8);
        }
        if (l < 2) {
            float bias = dc * ds;
            int b = batch[g];
            int f0 = half * 5;
            atomicAdd(&ps[b * NC + f0 + 0], dc * a0 + bias * b2s[f0 + 0]);
            atomicAdd(&ps[b * NC + f0 + 1], dc * a1 + bias * b2s[f0 + 1]);
            atomicAdd(&ps[b * NC + f0 + 2], dc * a2 + bias * b2s[f0 + 2]);
            atomicAdd(&ps[b * NC + f0 + 3], dc * a3 + bias * b2s[f0 + 3]);
            atomicAdd(&ps[b * NC + f0 + 4], dc * a4 + bias * b2s[f0 + 4]);
            if (half == 1) atomicAdd(&lc[b], 1.0f);
        }
    }
    __syncthreads();
    for (int idx = tid; idx < NG * NC; idx += 256) {
        float v = ps[idx];
        if (v != 0.f) atomicAdd(&psum[idx], v);
    }
    if (tid < NG) {
        float v = lc[tid];
        if (v != 0.f) atomicAdd(&cnt[tid], v);
    }
}

__global__ void k_final(const float* __restrict__ psum, const float* __restrict__ cnt,
                        float* __restrict__ out) {
    int g = threadIdx.x;
    if (g < NG) {
        float cg = fmaxf(cnt[g], 1.0f);
        float l[NC];
        float m = -1e30f;
#pragma unroll
        for (int c = 0; c < NC; ++c) { l[c] = psum[g * NC + c] / cg; m = fmaxf(m, l[c]); }
        float se = 0.f;
#pragma unroll
        for (int c = 0; c < NC; ++c) se += expf(l[c] - m);
        float lse = m + logf(se);
#pragma unroll
        for (int c = 0; c < NC; ++c) out[g * NC + c] = l[c] - lse;
    }
}

extern "C" void kernel_launch(void* const* d_in, const int* in_sizes, int n_in,
                              void* d_out, int out_size, void* d_ws, size_t ws_size,
                              hipStream_t stream) {
    const float* X   = (const float*)d_in[0];
    const int* ei    = (const int*)d_in[1];
    const int* batch = (const int*)d_in[2];
    const float* W1  = (const float*)d_in[4];
    const float* b1  = (const float*)d_in[5];
    const float* W2  = (const float*)d_in[6];
    const float* b2  = (const float*)d_in[7];
    float* out = (float*)d_out;

    int n = in_sizes[0] / NF;   // 100000
    int E = in_sizes[1] / 2;    // 1600000
    const int* row = ei;
    const int* col = ei + E;

    int nbuk = cdiv(n, 256);    // 391
    int CH = cdiv(E, NBLK);     // 782 <= KUNR*SBT

    char* p = (char*)d_ws;
    int*   gcnt   = (int*)p;   p += (size_t)NBUKMAX * GPAD * 4;   // \ one
    float* psum   = (float*)p; p += (size_t)NG * NC * 4;          //  | memset
    float* cnt    = (float*)p; p += (size_t)NG * 4;               // / region
    int*   packed2= (int*)p;   p += (size_t)NBUKMAX * CAP * 4;    // 13.1 MB (csr in place)
    int*   degE   = (int*)p;   p += (size_t)n * 4;
    int*   offset = (int*)p;   p += (size_t)n * 4;
    float* dis    = (float*)p; p += (size_t)n * 4;
    unsigned short* Gs = (unsigned short*)p; p += (size_t)n * RW * 2;
    unsigned short* S1 = (unsigned short*)p; p += (size_t)n * RW * 2;
    float* W12    = (float*)p; p += NF * NC * 4;
    float* c12    = (float*)p; p += 16 * 4;

    const int B = 256;
    size_t zbytes = (size_t)(NBUKMAX * GPAD + NG * NC + NG) * 4;   // ~28.4 KB

    hipMemsetAsync(gcnt, 0, zbytes, stream);
    k_sort<<<NBLK, SBT, 0, stream>>>(row, col, gcnt, packed2, W1, b1, W2,
                                     W12, c12, E, CH, nbuk);
    k_gemm<<<cdiv(n, 32), B, 0, stream>>>(X, W12, c12, Gs, n);
    k_p3<<<nbuk, 512, 0, stream>>>(packed2, gcnt, degE, offset, dis,
                                   (unsigned int*)Gs, n, nbuk);
    k_gather0<<<cdiv(n, 32), B, 0, stream>>>(Gs, packed2, offset, degE, dis, S1, n);
    k_gather_pool<<<cdiv(n, 32), B, 0, stream>>>(S1, packed2, offset, degE, dis, b2,
                                                 batch, psum, cnt, n);
    k_final<<<1, 64, 0, stream>>>(psum, cnt, out);
}

// Round 21
// 123.117 us; speedup vs baseline: 1.2508x; 1.2508x over previous
//
#include <hip/hip_runtime.h>
#include <hip/hip_bf16.h>

#define NF 128
#define NC 10
#define NG 64
#define NBLK 512      // sort blocks (2 per CU at 1024 thr)
#define SBT 1024      // sort block threads
#define NBUKMAX 400   // max buckets (n <= 102400)
#define GPAD 16       // ints per gcnt slot (64B line)
#define CAP 8192      // per-bucket capacity (mean 4092, sigma ~64)
#define RW 16         // ushorts/row (32B). half h (uint4): pk(f,f),pk(f,f),pk(f,0),f32 aux
#define SCSR 2112     // staged csr ints per gather block (expected ~512)
#define KUNR 4        // unroll depth: CH=3125 <= 4*1024

static inline int cdiv(int a, int b) { return (a + b - 1) / b; }

__device__ __forceinline__ float bf_lo(unsigned u) { return __uint_as_float(u << 16); }
__device__ __forceinline__ float bf_hi(unsigned u) { return __uint_as_float(u & 0xFFFF0000u); }
__device__ __forceinline__ unsigned pk_bf16(float a, float b) {
    unsigned ua = __float_as_uint(a), ub = __float_as_uint(b);
    ua = (ua + 0x7FFFu + ((ua >> 16) & 1u)) >> 16;
    ub = (ub + 0x7FFFu + ((ub >> 16) & 1u)) >> 16;
    return ua | (ub << 16);
}

// plain-add accumulate of one half-row (5 feats + aux)
#define ACC5(x4)                                    \
    a0 += bf_lo((x4).x); a1 += bf_hi((x4).x);       \
    a2 += bf_lo((x4).y); a3 += bf_hi((x4).y);       \
    a4 += bf_lo((x4).z); ds += __uint_as_float((x4).w);

// FMA accumulate scaled by the row's own aux
#define ACCF(x4) {                                  \
    float w_ = __uint_as_float((x4).w);             \
    a0 = fmaf(w_, bf_lo((x4).x), a0);               \
    a1 = fmaf(w_, bf_hi((x4).x), a1);               \
    a2 = fmaf(w_, bf_lo((x4).y), a2);               \
    a3 = fmaf(w_, bf_hi((x4).y), a3);               \
    a4 = fmaf(w_, bf_lo((x4).z), a4); }

// Bucket sort (r18 structure at 512 blocks = 2/CU): register-batched loads,
// LDS histogram, padded global reservation, scatter from registers.
// Block 1 additionally computes W12 = W1@W2, c12 = b1@W2 (once, to global).
__global__ __launch_bounds__(SBT) void k_sort(const int* __restrict__ row,
                                              const int* __restrict__ col,
                                              int* __restrict__ gcnt,
                                              int* __restrict__ packed2,
                                              const float* __restrict__ W1,
                                              const float* __restrict__ b1,
                                              const float* __restrict__ W2,
                                              float* __restrict__ W12,
                                              float* __restrict__ c12,
                                              int E, int CH, int nbuk) {
    __shared__ int h[NBUKMAX];
    __shared__ int hb[NBUKMAX];
    int blk = blockIdx.x, tid = threadIdx.x;
    int e0 = blk * CH;
    int ne = min(E - e0, CH);

    // batched loads: all independent, in flight together
    int cr[KUNR], rr[KUNR];
#pragma unroll
    for (int k = 0; k < KUNR; ++k) {
        int i = tid + k * SBT;
        if (i < ne) { cr[k] = col[e0 + i]; rr[k] = row[e0 + i]; }
        else { cr[k] = -1; rr[k] = 0; }
    }

    if (blk == 1) {
        for (int idx = tid; idx < NF * NC; idx += SBT) {
            int a = idx / NC, c = idx % NC;
            float s = 0.f;
            for (int m = 0; m < NF; ++m) s += W1[a * NF + m] * W2[m * NC + c];
            W12[idx] = s;
        }
        if (tid < NC) {
            float s = 0.f;
            for (int m = 0; m < NF; ++m) s += b1[m] * W2[m * NC + tid];
            c12[tid] = s;
        }
    }
    for (int i = tid; i < nbuk; i += SBT) h[i] = 0;
    __syncthreads();
#pragma unroll
    for (int k = 0; k < KUNR; ++k)
        if (cr[k] >= 0) atomicAdd(&h[cr[k] >> 8], 1);
    for (int i = tid + KUNR * SBT; i < ne; i += SBT)   // defensive tail
        atomicAdd(&h[col[e0 + i] >> 8], 1);
    __syncthreads();
    for (int i = tid; i < nbuk; i += SBT) {
        int c = h[i];
        hb[i] = c ? atomicAdd(&gcnt[(size_t)i * GPAD], c) : 0;
        h[i] = 0;
    }
    __syncthreads();
#pragma unroll
    for (int k = 0; k < KUNR; ++k) {
        if (cr[k] >= 0) {
            int c = cr[k];
            int b = c >> 8;
            int t = hb[b] + atomicAdd(&h[b], 1);
            if (t < CAP)
                packed2[(size_t)b * CAP + t] = rr[k] | ((c & 255) << 17);
        }
    }
    for (int i = tid + KUNR * SBT; i < ne; i += SBT) { // defensive tail
        int c = col[e0 + i];
        int b = c >> 8;
        int t = hb[b] + atomicAdd(&h[b], 1);
        if (t < CAP)
            packed2[(size_t)b * CAP + t] = row[e0 + i] | ((c & 255) << 17);
    }
}

// Dense GEMM, fully coalesced: 8 threads/row (seg = lane&7), lane-adjacent
// float4 loads. W12 LOADED from global (computed once by k_sort blk 1).
// Gs[node] = X@W12 + c12 (unscaled bf16, aux slots = 0, filled by k_p3).
__global__ __launch_bounds__(256) void k_gemm(const float* __restrict__ X,
                                              const float* __restrict__ W12,
                                              const float* __restrict__ c12,
                                              unsigned short* __restrict__ Gs,
                                              int n) {
    __shared__ float Wp[NF][13];   // 13-pad: seg-stride 52 -> distinct banks
    __shared__ float c12s[NC];
    int tid = threadIdx.x;
    for (int idx = tid; idx < NF * NC; idx += 256)
        Wp[idx / NC][idx % NC] = W12[idx];
    if (tid < NC) c12s[tid] = c12[tid];
    __syncthreads();

    int r = tid >> 3, seg = tid & 7;
    int gn = blockIdx.x * 32 + r;
    if (gn >= n) return;
    const float4* xb = reinterpret_cast<const float4*>(X + (size_t)gn * NF);
    float4 x0 = xb[0 * 8 + seg];
    float4 x1 = xb[1 * 8 + seg];
    float4 x2 = xb[2 * 8 + seg];
    float4 x3 = xb[3 * 8 + seg];

    float acc[NC];
#pragma unroll
    for (int c = 0; c < NC; ++c) acc[c] = 0.f;
    const float4 xs[4] = {x0, x1, x2, x3};
#pragma unroll
    for (int c = 0; c < 4; ++c) {
        float xv[4] = {xs[c].x, xs[c].y, xs[c].z, xs[c].w};
#pragma unroll
        for (int j = 0; j < 4; ++j) {
            int k = c * 32 + seg * 4 + j;
            float x = xv[j];
#pragma unroll
            for (int f = 0; f < NC; ++f) acc[f] = fmaf(x, Wp[k][f], acc[f]);
        }
    }
#pragma unroll
    for (int m = 1; m <= 4; m <<= 1) {
#pragma unroll
        for (int c = 0; c < NC; ++c) acc[c] += __shfl_xor(acc[c], m, 8);
    }
    if (seg < 2) {
        float v[NC];
#pragma unroll
        for (int c = 0; c < NC; ++c) v[c] = acc[c] + c12s[c];
        uint4* pw = (uint4*)(Gs + (size_t)gn * RW);
        if (seg == 0)
            pw[0] = make_uint4(pk_bf16(v[0], v[1]), pk_bf16(v[2], v[3]),
                               pk_bf16(v[4], 0.f), 0u);
        else
            pw[1] = make_uint4(pk_bf16(v[5], v[6]), pk_bf16(v[7], v[8]),
                               pk_bf16(v[9], 0.f), 0u);
    }
}

// P3 (r8 proven form, 512 threads): stage segment in LDS, count, scan,
// write csr IN PLACE over packed2; emits degE/offset/dis + Gs aux words.
__global__ __launch_bounds__(512) void k_p3(int* __restrict__ packed2,
                                            const int* __restrict__ gcnt,
                                            int* __restrict__ degE,
                                            int* __restrict__ offset,
                                            float* __restrict__ dis,
                                            unsigned int* __restrict__ Gu,
                                            int n, int nbuk) {
    __shared__ int cnt[256], inc[256], cnt2[256];
    __shared__ int sp[CAP];
    int b = blockIdx.x, tid = threadIdx.x;
    size_t bs = (size_t)b * CAP;
    int seg = min(gcnt[(size_t)b * GPAD], CAP);
    if (tid < 256) { cnt[tid] = 0; cnt2[tid] = 0; }
    for (int pos = tid; pos < seg; pos += 512) sp[pos] = packed2[bs + pos];
    __syncthreads();
    for (int pos = tid; pos < seg; pos += 512)
        atomicAdd(&cnt[(sp[pos] >> 17) & 255], 1);
    __syncthreads();
    if (tid < 256) inc[tid] = cnt[tid];
    __syncthreads();
    for (int s = 1; s < 256; s <<= 1) {
        int x = 0;
        if (tid < 256 && tid >= s) x = inc[tid - s];
        __syncthreads();
        if (tid < 256) inc[tid] += x;
        __syncthreads();
    }
    int node = b * 256 + tid;
    if (tid < 256 && node < n) {
        int d = cnt[tid];
        degE[node] = d;
        offset[node] = (int)bs + inc[tid] - d;
        float dv = rsqrtf((float)(d + 1));
        dis[node] = dv;
        unsigned ud = __float_as_uint(dv);
        Gu[(size_t)node * 8 + 3] = ud;   // half0 aux
        Gu[(size_t)node * 8 + 7] = ud;   // half1 aux
    }
    __syncthreads();
    for (int pos = tid; pos < seg; pos += 512) {
        int v = sp[pos];
        int l = (v >> 17) & 255;
        int t = atomicAdd(&cnt2[l], 1);
        packed2[bs + (inc[l] - cnt[l]) + t] = v & 0x1FFFF;
    }
}

// layer-1 gather: 8 lanes/node (4 nbr-groups x 2 halves), csr staged in LDS.
// FMA-scaled by each row's aux (=dis[r]); S1 = dis_c^2 * acc, aux = dis_c.
__global__ __launch_bounds__(256) void k_gather0(const unsigned short* __restrict__ Gs,
        const int* __restrict__ csr, const int* __restrict__ offset,
        const int* __restrict__ degE, const float* __restrict__ dis,
        unsigned short* __restrict__ S1, int n) {
    __shared__ int scsr[SCSR];
    int tid = threadIdx.x;
    int g0 = blockIdx.x * 32;
    int gL = min(g0 + 31, n - 1);
    int o0 = offset[g0];
    int total = offset[gL] + degE[gL] - o0;
    bool st = (total <= SCSR);
    if (st)
        for (int i = tid; i < total; i += 256) scsr[i] = csr[o0 + i];
    __syncthreads();

    int g = g0 + (tid >> 3);
    int l = tid & 7, grp = l >> 1, half = l & 1;
    if (g >= n) return;
    int o = offset[g], d = degE[g];
    int ol = o - o0;
    float dc = dis[g];
    const uint4* base = (const uint4*)Gs;
    float a0=0,a1=0,a2=0,a3=0,a4=0;
    if (grp == 0) { uint4 x = base[(size_t)g * 2 + half]; ACCF(x); }
    int j = grp;
    if (st) {
        while (j + 12 < d) {
            int r0 = scsr[ol + j], r1 = scsr[ol + j + 4];
            int r2 = scsr[ol + j + 8], r3 = scsr[ol + j + 12];
            uint4 x0 = base[(size_t)r0 * 2 + half];
            uint4 x1 = base[(size_t)r1 * 2 + half];
            uint4 x2 = base[(size_t)r2 * 2 + half];
            uint4 x3 = base[(size_t)r3 * 2 + half];
            ACCF(x0); ACCF(x1); ACCF(x2); ACCF(x3);
            j += 16;
        }
        for (; j < d; j += 4) {
            uint4 x = base[(size_t)scsr[ol + j] * 2 + half];
            ACCF(x);
        }
    } else {
        for (; j < d; j += 4) {
            uint4 x = base[(size_t)csr[o + j] * 2 + half];
            ACCF(x);
        }
    }
#pragma unroll
    for (int m = 2; m <= 4; m <<= 1) {
        a0 += __shfl_xor(a0, m, 8); a1 += __shfl_xor(a1, m, 8);
        a2 += __shfl_xor(a2, m, 8); a3 += __shfl_xor(a3, m, 8);
        a4 += __shfl_xor(a4, m, 8);
    }
    if (l < 2) {
        float s = dc * dc;
        uint4* pw = (uint4*)(S1 + (size_t)g * RW);
        pw[half] = make_uint4(pk_bf16(a0 * s, a1 * s), pk_bf16(a2 * s, a3 * s),
                              pk_bf16(a4 * s, 0.f), __float_as_uint(dc));
    }
}

// layer-2 gather + bias + fused mean-pool; csr staged in LDS. Rows pre-scaled.
__global__ __launch_bounds__(256) void k_gather_pool(const unsigned short* __restrict__ S1,
        const int* __restrict__ csr, const int* __restrict__ offset,
        const int* __restrict__ degE, const float* __restrict__ dis,
        const float* __restrict__ b2, const int* __restrict__ batch,
        float* __restrict__ psum, float* __restrict__ cnt, int n) {
    __shared__ float ps[NG * NC];
    __shared__ float lc[NG];
    __shared__ float b2s[NC];
    __shared__ int scsr[SCSR];
    int tid = threadIdx.x;
    for (int idx = tid; idx < NG * NC; idx += 256) ps[idx] = 0.f;
    if (tid < NG) lc[tid] = 0.f;
    if (tid < NC) b2s[tid] = b2[tid];

    int g0 = blockIdx.x * 32;
    int gL = min(g0 + 31, n - 1);
    int o0 = offset[g0];
    int total = offset[gL] + degE[gL] - o0;
    bool st = (total <= SCSR);
    if (st)
        for (int i = tid; i < total; i += 256) scsr[i] = csr[o0 + i];
    __syncthreads();

    int g = g0 + (tid >> 3);
    int l = tid & 7, grp = l >> 1, half = l & 1;
    if (g < n) {
        int o = offset[g], d = degE[g];
        int ol = o - o0;
        float dc = dis[g];
        const uint4* base = (const uint4*)S1;
        float a0=0,a1=0,a2=0,a3=0,a4=0, ds=0;
        if (grp == 0) { uint4 x = base[(size_t)g * 2 + half]; ACC5(x); }
        int j = grp;
        if (st) {
            while (j + 12 < d) {
                int r0 = scsr[ol + j], r1 = scsr[ol + j + 4];
                int r2 = scsr[ol + j + 8], r3 = scsr[ol + j + 12];
                uint4 x0 = base[(size_t)r0 * 2 + half];
                uint4 x1 = base[(size_t)r1 * 2 + half];
                uint4 x2 = base[(size_t)r2 * 2 + half];
                uint4 x3 = base[(size_t)r3 * 2 + half];
                ACC5(x0); ACC5(x1); ACC5(x2); ACC5(x3);
                j += 16;
            }
            for (; j < d; j += 4) {
                uint4 x = base[(size_t)scsr[ol + j] * 2 + half];
                ACC5(x);
            }
        } else {
            for (; j < d; j += 4) {
                uint4 x = base[(size_t)csr[o + j] * 2 + half];
                ACC5(x);
            }
        }
#pragma unroll
        for (int m = 2; m <= 4; m <<= 1) {
            a0 += __shfl_xor(a0, m, 8); a1 += __shfl_xor(a1, m, 8);
            a2 += __shfl_xor(a2, m, 8); a3 += __shfl_xor(a3, m, 8);
            a4 += __shfl_xor(a4, m, 8); ds += __shfl_xor(ds, m, 8);
        }
        if (l < 2) {
            float bias = dc * ds;
            int b = batch[g];
            int f0 = half * 5;
            atomicAdd(&ps[b * NC + f0 + 0], dc * a0 + bias * b2s[f0 + 0]);
            atomicAdd(&ps[b * NC + f0 + 1], dc * a1 + bias * b2s[f0 + 1]);
            atomicAdd(&ps[b * NC + f0 + 2], dc * a2 + bias * b2s[f0 + 2]);
            atomicAdd(&ps[b * NC + f0 + 3], dc * a3 + bias * b2s[f0 + 3]);
            atomicAdd(&ps[b * NC + f0 + 4], dc * a4 + bias * b2s[f0 + 4]);
            if (half == 1) atomicAdd(&lc[b], 1.0f);
        }
    }
    __syncthreads();
    for (int idx = tid; idx < NG * NC; idx += 256) {
        float v = ps[idx];
        if (v != 0.f) atomicAdd(&psum[idx], v);
    }
    if (tid < NG) {
        float v = lc[tid];
        if (v != 0.f) atomicAdd(&cnt[tid], v);
    }
}

__global__ void k_final(const float* __restrict__ psum, const float* __restrict__ cnt,
                        float* __restrict__ out) {
    int g = threadIdx.x;
    if (g < NG) {
        float cg = fmaxf(cnt[g], 1.0f);
        float l[NC];
        float m = -1e30f;
#pragma unroll
        for (int c = 0; c < NC; ++c) { l[c] = psum[g * NC + c] / cg; m = fmaxf(m, l[c]); }
        float se = 0.f;
#pragma unroll
        for (int c = 0; c < NC; ++c) se += expf(l[c] - m);
        float lse = m + logf(se);
#pragma unroll
        for (int c = 0; c < NC; ++c) out[g * NC + c] = l[c] - lse;
    }
}

extern "C" void kernel_launch(void* const* d_in, const int* in_sizes, int n_in,
                              void* d_out, int out_size, void* d_ws, size_t ws_size,
                              hipStream_t stream) {
    const float* X   = (const float*)d_in[0];
    const int* ei    = (const int*)d_in[1];
    const int* batch = (const int*)d_in[2];
    const float* W1  = (const float*)d_in[4];
    const float* b1  = (const float*)d_in[5];
    const float* W2  = (const float*)d_in[6];
    const float* b2  = (const float*)d_in[7];
    float* out = (float*)d_out;

    int n = in_sizes[0] / NF;   // 100000
    int E = in_sizes[1] / 2;    // 1600000
    const int* row = ei;
    const int* col = ei + E;

    int nbuk = cdiv(n, 256);    // 391
    int CH = cdiv(E, NBLK);     // 3125 <= KUNR*SBT

    char* p = (char*)d_ws;
    int*   gcnt   = (int*)p;   p += (size_t)NBUKMAX * GPAD * 4;   // \ one
    float* psum   = (float*)p; p += (size_t)NG * NC * 4;          //  | memset
    float* cnt    = (float*)p; p += (size_t)NG * 4;               // / region
    int*   packed2= (int*)p;   p += (size_t)NBUKMAX * CAP * 4;    // 13.1 MB (csr in place)
    int*   degE   = (int*)p;   p += (size_t)n * 4;
    int*   offset = (int*)p;   p += (size_t)n * 4;
    float* dis    = (float*)p; p += (size_t)n * 4;
    unsigned short* Gs = (unsigned short*)p; p += (size_t)n * RW * 2;
    unsigned short* S1 = (unsigned short*)p; p += (size_t)n * RW * 2;
    float* W12    = (float*)p; p += NF * NC * 4;
    float* c12    = (float*)p; p += 16 * 4;

    const int B = 256;
    size_t zbytes = (size_t)(NBUKMAX * GPAD + NG * NC + NG) * 4;   // ~28.4 KB

    hipMemsetAsync(gcnt, 0, zbytes, stream);
    k_sort<<<NBLK, SBT, 0, stream>>>(row, col, gcnt, packed2, W1, b1, W2,
                                     W12, c12, E, CH, nbuk);
    k_gemm<<<cdiv(n, 32), B, 0, stream>>>(X, W12, c12, Gs, n);
    k_p3<<<nbuk, 512, 0, stream>>>(packed2, gcnt, degE, offset, dis,
                                   (unsigned int*)Gs, n, nbuk);
    k_gather0<<<cdiv(n, 32), B, 0, stream>>>(Gs, packed2, offset, degE, dis, S1, n);
    k_gather_pool<<<cdiv(n, 32), B, 0, stream>>>(S1, packed2, offset, degE, dis, b2,
                                                 batch, psum, cnt, n);
    k_final<<<1, 64, 0, stream>>>(psum, cnt, out);
}

// Round 22
// 119.695 us; speedup vs baseline: 1.2866x; 1.0286x over previous
//
#include <hip/hip_runtime.h>
#include <hip/hip_bf16.h>

#define NF 128
#define NC 10
#define NG 64
#define NBLK 256      // sort blocks
#define NBUKMAX 400   // max buckets (n <= 102400)
#define GPAD 16       // ints per gcnt slot (64B line)
#define CAP 8192      // per-bucket capacity (mean 4092, sigma ~64)
#define RW 16         // ushorts/row (32B). half h (uint4): pk(f,f),pk(f,f),pk(f,0),f32 aux
#define SCSR 2112     // staged csr ints per gather block (expected ~512)
#define KUNR 7        // unroll depth: CH=6250 <= 7*1024

static inline int cdiv(int a, int b) { return (a + b - 1) / b; }

__device__ __forceinline__ float bf_lo(unsigned u) { return __uint_as_float(u << 16); }
__device__ __forceinline__ float bf_hi(unsigned u) { return __uint_as_float(u & 0xFFFF0000u); }
__device__ __forceinline__ unsigned pk_bf16(float a, float b) {
    unsigned ua = __float_as_uint(a), ub = __float_as_uint(b);
    ua = (ua + 0x7FFFu + ((ua >> 16) & 1u)) >> 16;
    ub = (ub + 0x7FFFu + ((ub >> 16) & 1u)) >> 16;
    return ua | (ub << 16);
}

// plain-add accumulate of one half-row (5 feats + aux)
#define ACC5(x4)                                    \
    a0 += bf_lo((x4).x); a1 += bf_hi((x4).x);       \
    a2 += bf_lo((x4).y); a3 += bf_hi((x4).y);       \
    a4 += bf_lo((x4).z); ds += __uint_as_float((x4).w);

// FMA accumulate scaled by the row's own aux
#define ACCF(x4) {                                  \
    float w_ = __uint_as_float((x4).w);             \
    a0 = fmaf(w_, bf_lo((x4).x), a0);               \
    a1 = fmaf(w_, bf_hi((x4).x), a1);               \
    a2 = fmaf(w_, bf_lo((x4).y), a2);               \
    a3 = fmaf(w_, bf_hi((x4).y), a3);               \
    a4 = fmaf(w_, bf_lo((x4).z), a4); }

// zero gcnt (padded) + psum + cnt — replaces hipMemsetAsync, whose rocclr
// fill kernel measured ~40us for 28KB in graph replay (counter evidence r17/r18)
__global__ __launch_bounds__(1024) void k_zero(int* __restrict__ z, int nz) {
    int i = blockIdx.x * 1024 + threadIdx.x;
    if (i < nz) z[i] = 0;
}

// Bucket sort with register-batched edges (r18 proven form, 40us):
// all col/row loads issued up front (7-deep MLP), LDS histogram, padded
// global reservation, scatter from registers.
// Block 1 additionally computes W12 = W1@W2, c12 = b1@W2 (once, to global).
__global__ __launch_bounds__(1024) void k_sort(const int* __restrict__ row,
                                               const int* __restrict__ col,
                                               int* __restrict__ gcnt,
                                               int* __restrict__ packed2,
                                               const float* __restrict__ W1,
                                               const float* __restrict__ b1,
                                               const float* __restrict__ W2,
                                               float* __restrict__ W12,
                                               float* __restrict__ c12,
                                               int E, int CH, int nbuk) {
    __shared__ int h[NBUKMAX];
    __shared__ int hb[NBUKMAX];
    int blk = blockIdx.x, tid = threadIdx.x;
    int e0 = blk * CH;
    int ne = min(E - e0, CH);

    int cr[KUNR], rr[KUNR];
#pragma unroll
    for (int k = 0; k < KUNR; ++k) {
        int i = tid + k * 1024;
        if (i < ne) { cr[k] = col[e0 + i]; rr[k] = row[e0 + i]; }
        else { cr[k] = -1; rr[k] = 0; }
    }

    if (blk == 1) {
        for (int idx = tid; idx < NF * NC; idx += 1024) {
            int a = idx / NC, c = idx % NC;
            float s = 0.f;
            for (int m = 0; m < NF; ++m) s += W1[a * NF + m] * W2[m * NC + c];
            W12[idx] = s;
        }
        if (tid < NC) {
            float s = 0.f;
            for (int m = 0; m < NF; ++m) s += b1[m] * W2[m * NC + tid];
            c12[tid] = s;
        }
    }
    for (int i = tid; i < nbuk; i += 1024) h[i] = 0;
    __syncthreads();
#pragma unroll
    for (int k = 0; k < KUNR; ++k)
        if (cr[k] >= 0) atomicAdd(&h[cr[k] >> 8], 1);
    for (int i = tid + KUNR * 1024; i < ne; i += 1024)   // defensive tail
        atomicAdd(&h[col[e0 + i] >> 8], 1);
    __syncthreads();
    for (int i = tid; i < nbuk; i += 1024) {
        int c = h[i];
        hb[i] = c ? atomicAdd(&gcnt[(size_t)i * GPAD], c) : 0;
        h[i] = 0;
    }
    __syncthreads();
#pragma unroll
    for (int k = 0; k < KUNR; ++k) {
        if (cr[k] >= 0) {
            int c = cr[k];
            int b = c >> 8;
            int t = hb[b] + atomicAdd(&h[b], 1);
            if (t < CAP)
                packed2[(size_t)b * CAP + t] = rr[k] | ((c & 255) << 17);
        }
    }
    for (int i = tid + KUNR * 1024; i < ne; i += 1024) { // defensive tail
        int c = col[e0 + i];
        int b = c >> 8;
        int t = hb[b] + atomicAdd(&h[b], 1);
        if (t < CAP)
            packed2[(size_t)b * CAP + t] = row[e0 + i] | ((c & 255) << 17);
    }
}

// Dense GEMM, fully coalesced: 8 threads/row (seg = lane&7), lane-adjacent
// float4 loads. W12 LOADED from global (computed once by k_sort blk 1).
// Gs[node] = X@W12 + c12 (unscaled bf16, aux slots = 0, filled by k_p3).
__global__ __launch_bounds__(256) void k_gemm(const float* __restrict__ X,
                                              const float* __restrict__ W12,
                                              const float* __restrict__ c12,
                                              unsigned short* __restrict__ Gs,
                                              int n) {
    __shared__ float Wp[NF][13];   // 13-pad: seg-stride 52 -> distinct banks
    __shared__ float c12s[NC];
    int tid = threadIdx.x;
    for (int idx = tid; idx < NF * NC; idx += 256)
        Wp[idx / NC][idx % NC] = W12[idx];
    if (tid < NC) c12s[tid] = c12[tid];
    __syncthreads();

    int r = tid >> 3, seg = tid & 7;
    int gn = blockIdx.x * 32 + r;
    if (gn >= n) return;
    const float4* xb = reinterpret_cast<const float4*>(X + (size_t)gn * NF);
    float4 x0 = xb[0 * 8 + seg];
    float4 x1 = xb[1 * 8 + seg];
    float4 x2 = xb[2 * 8 + seg];
    float4 x3 = xb[3 * 8 + seg];

    float acc[NC];
#pragma unroll
    for (int c = 0; c < NC; ++c) acc[c] = 0.f;
    const float4 xs[4] = {x0, x1, x2, x3};
#pragma unroll
    for (int c = 0; c < 4; ++c) {
        float xv[4] = {xs[c].x, xs[c].y, xs[c].z, xs[c].w};
#pragma unroll
        for (int j = 0; j < 4; ++j) {
            int k = c * 32 + seg * 4 + j;
            float x = xv[j];
#pragma unroll
            for (int f = 0; f < NC; ++f) acc[f] = fmaf(x, Wp[k][f], acc[f]);
        }
    }
#pragma unroll
    for (int m = 1; m <= 4; m <<= 1) {
#pragma unroll
        for (int c = 0; c < NC; ++c) acc[c] += __shfl_xor(acc[c], m, 8);
    }
    if (seg < 2) {
        float v[NC];
#pragma unroll
        for (int c = 0; c < NC; ++c) v[c] = acc[c] + c12s[c];
        uint4* pw = (uint4*)(Gs + (size_t)gn * RW);
        if (seg == 0)
            pw[0] = make_uint4(pk_bf16(v[0], v[1]), pk_bf16(v[2], v[3]),
                               pk_bf16(v[4], 0.f), 0u);
        else
            pw[1] = make_uint4(pk_bf16(v[5], v[6]), pk_bf16(v[7], v[8]),
                               pk_bf16(v[9], 0.f), 0u);
    }
}

// P3 (r8 proven form, 512 threads): stage segment in LDS, count, scan,
// write csr IN PLACE over packed2; emits degE/offset/dis + Gs aux words.
__global__ __launch_bounds__(512) void k_p3(int* __restrict__ packed2,
                                            const int* __restrict__ gcnt,
                                            int* __restrict__ degE,
                                            int* __restrict__ offset,
                                            float* __restrict__ dis,
                                            unsigned int* __restrict__ Gu,
                                            int n, int nbuk) {
    __shared__ int cnt[256], inc[256], cnt2[256];
    __shared__ int sp[CAP];
    int b = blockIdx.x, tid = threadIdx.x;
    size_t bs = (size_t)b * CAP;
    int seg = min(gcnt[(size_t)b * GPAD], CAP);
    if (tid < 256) { cnt[tid] = 0; cnt2[tid] = 0; }
    for (int pos = tid; pos < seg; pos += 512) sp[pos] = packed2[bs + pos];
    __syncthreads();
    for (int pos = tid; pos < seg; pos += 512)
        atomicAdd(&cnt[(sp[pos] >> 17) & 255], 1);
    __syncthreads();
    if (tid < 256) inc[tid] = cnt[tid];
    __syncthreads();
    for (int s = 1; s < 256; s <<= 1) {
        int x = 0;
        if (tid < 256 && tid >= s) x = inc[tid - s];
        __syncthreads();
        if (tid < 256) inc[tid] += x;
        __syncthreads();
    }
    int node = b * 256 + tid;
    if (tid < 256 && node < n) {
        int d = cnt[tid];
        degE[node] = d;
        offset[node] = (int)bs + inc[tid] - d;
        float dv = rsqrtf((float)(d + 1));
        dis[node] = dv;
        unsigned ud = __float_as_uint(dv);
        Gu[(size_t)node * 8 + 3] = ud;   // half0 aux
        Gu[(size_t)node * 8 + 7] = ud;   // half1 aux
    }
    __syncthreads();
    for (int pos = tid; pos < seg; pos += 512) {
        int v = sp[pos];
        int l = (v >> 17) & 255;
        int t = atomicAdd(&cnt2[l], 1);
        packed2[bs + (inc[l] - cnt[l]) + t] = v & 0x1FFFF;
    }
}

// layer-1 gather: 8 lanes/node (4 nbr-groups x 2 halves), csr staged in LDS.
// FMA-scaled by each row's aux (=dis[r]); S1 = dis_c^2 * acc, aux = dis_c.
__global__ __launch_bounds__(256) void k_gather0(const unsigned short* __restrict__ Gs,
        const int* __restrict__ csr, const int* __restrict__ offset,
        const int* __restrict__ degE, const float* __restrict__ dis,
        unsigned short* __restrict__ S1, int n) {
    __shared__ int scsr[SCSR];
    int tid = threadIdx.x;
    int g0 = blockIdx.x * 32;
    int gL = min(g0 + 31, n - 1);
    int o0 = offset[g0];
    int total = offset[gL] + degE[gL] - o0;
    bool st = (total <= SCSR);
    if (st)
        for (int i = tid; i < total; i += 256) scsr[i] = csr[o0 + i];
    __syncthreads();

    int g = g0 + (tid >> 3);
    int l = tid & 7, grp = l >> 1, half = l & 1;
    if (g >= n) return;
    int o = offset[g], d = degE[g];
    int ol = o - o0;
    float dc = dis[g];
    const uint4* base = (const uint4*)Gs;
    float a0=0,a1=0,a2=0,a3=0,a4=0;
    if (grp == 0) { uint4 x = base[(size_t)g * 2 + half]; ACCF(x); }
    int j = grp;
    if (st) {
        while (j + 12 < d) {
            int r0 = scsr[ol + j], r1 = scsr[ol + j + 4];
            int r2 = scsr[ol + j + 8], r3 = scsr[ol + j + 12];
            uint4 x0 = base[(size_t)r0 * 2 + half];
            uint4 x1 = base[(size_t)r1 * 2 + half];
            uint4 x2 = base[(size_t)r2 * 2 + half];
            uint4 x3 = base[(size_t)r3 * 2 + half];
            ACCF(x0); ACCF(x1); ACCF(x2); ACCF(x3);
            j += 16;
        }
        for (; j < d; j += 4) {
            uint4 x = base[(size_t)scsr[ol + j] * 2 + half];
            ACCF(x);
        }
    } else {
        for (; j < d; j += 4) {
            uint4 x = base[(size_t)csr[o + j] * 2 + half];
            ACCF(x);
        }
    }
#pragma unroll
    for (int m = 2; m <= 4; m <<= 1) {
        a0 += __shfl_xor(a0, m, 8); a1 += __shfl_xor(a1, m, 8);
        a2 += __shfl_xor(a2, m, 8); a3 += __shfl_xor(a3, m, 8);
        a4 += __shfl_xor(a4, m, 8);
    }
    if (l < 2) {
        float s = dc * dc;
        uint4* pw = (uint4*)(S1 + (size_t)g * RW);
        pw[half] = make_uint4(pk_bf16(a0 * s, a1 * s), pk_bf16(a2 * s, a3 * s),
                              pk_bf16(a4 * s, 0.f), __float_as_uint(dc));
    }
}

// layer-2 gather + bias + fused mean-pool; csr staged in LDS. Rows pre-scaled.
__global__ __launch_bounds__(256) void k_gather_pool(const unsigned short* __restrict__ S1,
        const int* __restrict__ csr, const int* __restrict__ offset,
        const int* __restrict__ degE, const float* __restrict__ dis,
        const float* __restrict__ b2, const int* __restrict__ batch,
        float* __restrict__ psum, float* __restrict__ cnt, int n) {
    __shared__ float ps[NG * NC];
    __shared__ float lc[NG];
    __shared__ float b2s[NC];
    __shared__ int scsr[SCSR];
    int tid = threadIdx.x;
    for (int idx = tid; idx < NG * NC; idx += 256) ps[idx] = 0.f;
    if (tid < NG) lc[tid] = 0.f;
    if (tid < NC) b2s[tid] = b2[tid];

    int g0 = blockIdx.x * 32;
    int gL = min(g0 + 31, n - 1);
    int o0 = offset[g0];
    int total = offset[gL] + degE[gL] - o0;
    bool st = (total <= SCSR);
    if (st)
        for (int i = tid; i < total; i += 256) scsr[i] = csr[o0 + i];
    __syncthreads();

    int g = g0 + (tid >> 3);
    int l = tid & 7, grp = l >> 1, half = l & 1;
    if (g < n) {
        int o = offset[g], d = degE[g];
        int ol = o - o0;
        float dc = dis[g];
        const uint4* base = (const uint4*)S1;
        float a0=0,a1=0,a2=0,a3=0,a4=0, ds=0;
        if (grp == 0) { uint4 x = base[(size_t)g * 2 + half]; ACC5(x); }
        int j = grp;
        if (st) {
            while (j + 12 < d) {
                int r0 = scsr[ol + j], r1 = scsr[ol + j + 4];
                int r2 = scsr[ol + j + 8], r3 = scsr[ol + j + 12];
                uint4 x0 = base[(size_t)r0 * 2 + half];
                uint4 x1 = base[(size_t)r1 * 2 + half];
                uint4 x2 = base[(size_t)r2 * 2 + half];
                uint4 x3 = base[(size_t)r3 * 2 + half];
                ACC5(x0); ACC5(x1); ACC5(x2); ACC5(x3);
                j += 16;
            }
            for (; j < d; j += 4) {
                uint4 x = base[(size_t)scsr[ol + j] * 2 + half];
                ACC5(x);
            }
        } else {
            for (; j < d; j += 4) {
                uint4 x = base[(size_t)csr[o + j] * 2 + half];
                ACC5(x);
            }
        }
#pragma unroll
        for (int m = 2; m <= 4; m <<= 1) {
            a0 += __shfl_xor(a0, m, 8); a1 += __shfl_xor(a1, m, 8);
            a2 += __shfl_xor(a2, m, 8); a3 += __shfl_xor(a3, m, 8);
            a4 += __shfl_xor(a4, m, 8); ds += __shfl_xor(ds, m, 8);
        }
        if (l < 2) {
            float bias = dc * ds;
            int b = batch[g];
            int f0 = half * 5;
            atomicAdd(&ps[b * NC + f0 + 0], dc * a0 + bias * b2s[f0 + 0]);
            atomicAdd(&ps[b * NC + f0 + 1], dc * a1 + bias * b2s[f0 + 1]);
            atomicAdd(&ps[b * NC + f0 + 2], dc * a2 + bias * b2s[f0 + 2]);
            atomicAdd(&ps[b * NC + f0 + 3], dc * a3 + bias * b2s[f0 + 3]);
            atomicAdd(&ps[b * NC + f0 + 4], dc * a4 + bias * b2s[f0 + 4]);
            if (half == 1) atomicAdd(&lc[b], 1.0f);
        }
    }
    __syncthreads();
    for (int idx = tid; idx < NG * NC; idx += 256) {
        float v = ps[idx];
        if (v != 0.f) atomicAdd(&psum[idx], v);
    }
    if (tid < NG) {
        float v = lc[tid];
        if (v != 0.f) atomicAdd(&cnt[tid], v);
    }
}

__global__ void k_final(const float* __restrict__ psum, const float* __restrict__ cnt,
                        float* __restrict__ out) {
    int g = threadIdx.x;
    if (g < NG) {
        float cg = fmaxf(cnt[g], 1.0f);
        float l[NC];
        float m = -1e30f;
#pragma unroll
        for (int c = 0; c < NC; ++c) { l[c] = psum[g * NC + c] / cg; m = fmaxf(m, l[c]); }
        float se = 0.f;
#pragma unroll
        for (int c = 0; c < NC; ++c) se += expf(l[c] - m);
        float lse = m + logf(se);
#pragma unroll
        for (int c = 0; c < NC; ++c) out[g * NC + c] = l[c] - lse;
    }
}

extern "C" void kernel_launch(void* const* d_in, const int* in_sizes, int n_in,
                              void* d_out, int out_size, void* d_ws, size_t ws_size,
                              hipStream_t stream) {
    const float* X   = (const float*)d_in[0];
    const int* ei    = (const int*)d_in[1];
    const int* batch = (const int*)d_in[2];
    const float* W1  = (const float*)d_in[4];
    const float* b1  = (const float*)d_in[5];
    const float* W2  = (const float*)d_in[6];
    const float* b2  = (const float*)d_in[7];
    float* out = (float*)d_out;

    int n = in_sizes[0] / NF;   // 100000
    int E = in_sizes[1] / 2;    // 1600000
    const int* row = ei;
    const int* col = ei + E;

    int nbuk = cdiv(n, 256);    // 391
    int CH = cdiv(E, NBLK);     // 6250

    char* p = (char*)d_ws;
    int*   gcnt   = (int*)p;   p += (size_t)NBUKMAX * GPAD * 4;   // \ one
    float* psum   = (float*)p; p += (size_t)NG * NC * 4;          //  | zero
    float* cnt    = (float*)p; p += (size_t)NG * 4;               // / region
    int*   packed2= (int*)p;   p += (size_t)NBUKMAX * CAP * 4;    // 13.1 MB (csr in place)
    int*   degE   = (int*)p;   p += (size_t)n * 4;
    int*   offset = (int*)p;   p += (size_t)n * 4;
    float* dis    = (float*)p; p += (size_t)n * 4;
    unsigned short* Gs = (unsigned short*)p; p += (size_t)n * RW * 2;
    unsigned short* S1 = (unsigned short*)p; p += (size_t)n * RW * 2;
    float* W12    = (float*)p; p += NF * NC * 4;
    float* c12    = (float*)p; p += 16 * 4;

    const int B = 256;
    int nz = NBUKMAX * GPAD + NG * NC + NG;   // 7104 ints

    k_zero<<<cdiv(nz, 1024), 1024, 0, stream>>>(gcnt, nz);
    k_sort<<<NBLK, 1024, 0, stream>>>(row, col, gcnt, packed2, W1, b1, W2,
                                      W12, c12, E, CH, nbuk);
    k_gemm<<<cdiv(n, 32), B, 0, stream>>>(X, W12, c12, Gs, n);
    k_p3<<<nbuk, 512, 0, stream>>>(packed2, gcnt, degE, offset, dis,
                                   (unsigned int*)Gs, n, nbuk);
    k_gather0<<<cdiv(n, 32), B, 0, stream>>>(Gs, packed2, offset, degE, dis, S1, n);
    k_gather_pool<<<cdiv(n, 32), B, 0, stream>>>(S1, packed2, offset, degE, dis, b2,
                                                 batch, psum, cnt, n);
    k_final<<<1, 64, 0, stream>>>(psum, cnt, out);
}

// Round 23
// 105.219 us; speedup vs baseline: 1.4636x; 1.1376x over previous
//
#include <hip/hip_runtime.h>
#include <hip/hip_bf16.h>

#define NF 128
#define NC 10
#define NG 64
#define NBLK 256      // sort blocks
#define NBUKMAX 400   // max buckets (n <= 102400)
#define GPAD 16       // ints per gcnt slot (64B line)
#define CAP 8192      // per-bucket capacity (mean 4092, sigma ~64)
#define RW 16         // ushorts/row (32B). half h (uint4): pk(f,f),pk(f,f),pk(f,0),f32 aux
#define SCSR 2112     // staged csr ints per gather block (expected ~512)
#define KUNR 7        // unroll depth: CH=6250 <= 7*1024
#define NZB 7         // zero-role blocks in k_pre

static inline int cdiv(int a, int b) { return (a + b - 1) / b; }

__device__ __forceinline__ float bf_lo(unsigned u) { return __uint_as_float(u << 16); }
__device__ __forceinline__ float bf_hi(unsigned u) { return __uint_as_float(u & 0xFFFF0000u); }
__device__ __forceinline__ unsigned pk_bf16(float a, float b) {
    unsigned ua = __float_as_uint(a), ub = __float_as_uint(b);
    ua = (ua + 0x7FFFu + ((ua >> 16) & 1u)) >> 16;
    ub = (ub + 0x7FFFu + ((ub >> 16) & 1u)) >> 16;
    return ua | (ub << 16);
}

// plain-add accumulate of one half-row (5 feats + aux)
#define ACC5(x4)                                    \
    a0 += bf_lo((x4).x); a1 += bf_hi((x4).x);       \
    a2 += bf_lo((x4).y); a3 += bf_hi((x4).y);       \
    a4 += bf_lo((x4).z); ds += __uint_as_float((x4).w);

// FMA accumulate scaled by the row's own aux
#define ACCF(x4) {                                  \
    float w_ = __uint_as_float((x4).w);             \
    a0 = fmaf(w_, bf_lo((x4).x), a0);               \
    a1 = fmaf(w_, bf_hi((x4).x), a1);               \
    a2 = fmaf(w_, bf_lo((x4).y), a2);               \
    a3 = fmaf(w_, bf_hi((x4).y), a3);               \
    a4 = fmaf(w_, bf_lo((x4).z), a4); }

// k_pre: blocks 0..6 zero gcnt/psum/cnt; blocks 7.. compute W12 = W1@W2 and
// c12 = b1@W2 with 8 threads/dot (all loads independent -> one latency hop,
// not the 128-deep serial chain that straggled inside k_sort since r8).
__global__ __launch_bounds__(1024) void k_pre(int* __restrict__ z, int nz,
                                              const float* __restrict__ W1,
                                              const float* __restrict__ b1,
                                              const float* __restrict__ W2,
                                              float* __restrict__ W12,
                                              float* __restrict__ c12) {
    int blk = blockIdx.x, tid = threadIdx.x;
    if (blk < NZB) {
        int i = blk * 1024 + tid;
        if (i < nz) z[i] = 0;
        return;
    }
    int d = (blk - NZB) * 128 + (tid >> 3);   // dot index: 0..1279 W12, 1280..1289 c12
    int seg = tid & 7;
    if (d >= NF * NC + NC) return;
    int m0 = seg * 16;
    const float* w1p;
    int c;
    if (d < NF * NC) { w1p = W1 + (size_t)(d / NC) * NF; c = d % NC; }
    else             { w1p = b1;                          c = d - NF * NC; }
    // 16 independent W2 loads + 4 independent float4 W1 loads
    float w2v[16];
#pragma unroll
    for (int j = 0; j < 16; ++j) w2v[j] = W2[(m0 + j) * NC + c];
    const float4* w1q = reinterpret_cast<const float4*>(w1p + m0);
    float4 v0 = w1q[0], v1 = w1q[1], v2 = w1q[2], v3 = w1q[3];
    float s = v0.x * w2v[0] + v0.y * w2v[1] + v0.z * w2v[2] + v0.w * w2v[3]
            + v1.x * w2v[4] + v1.y * w2v[5] + v1.z * w2v[6] + v1.w * w2v[7]
            + v2.x * w2v[8] + v2.y * w2v[9] + v2.z * w2v[10] + v2.w * w2v[11]
            + v3.x * w2v[12] + v3.y * w2v[13] + v3.z * w2v[14] + v3.w * w2v[15];
#pragma unroll
    for (int m = 1; m <= 4; m <<= 1) s += __shfl_xor(s, m, 8);
    if (seg == 0) {
        if (d < NF * NC) W12[d] = s;
        else c12[d - NF * NC] = s;
    }
}

// Bucket sort with register-batched edges (r18 proven form, minus the W12
// straggler): all col/row loads issued up front (7-deep MLP), LDS histogram,
// padded global reservation, scatter from registers.
__global__ __launch_bounds__(1024) void k_sort(const int* __restrict__ row,
                                               const int* __restrict__ col,
                                               int* __restrict__ gcnt,
                                               int* __restrict__ packed2,
                                               int E, int CH, int nbuk) {
    __shared__ int h[NBUKMAX];
    __shared__ int hb[NBUKMAX];
    int blk = blockIdx.x, tid = threadIdx.x;
    int e0 = blk * CH;
    int ne = min(E - e0, CH);

    int cr[KUNR], rr[KUNR];
#pragma unroll
    for (int k = 0; k < KUNR; ++k) {
        int i = tid + k * 1024;
        if (i < ne) { cr[k] = col[e0 + i]; rr[k] = row[e0 + i]; }
        else { cr[k] = -1; rr[k] = 0; }
    }

    for (int i = tid; i < nbuk; i += 1024) h[i] = 0;
    __syncthreads();
#pragma unroll
    for (int k = 0; k < KUNR; ++k)
        if (cr[k] >= 0) atomicAdd(&h[cr[k] >> 8], 1);
    for (int i = tid + KUNR * 1024; i < ne; i += 1024)   // defensive tail
        atomicAdd(&h[col[e0 + i] >> 8], 1);
    __syncthreads();
    for (int i = tid; i < nbuk; i += 1024) {
        int c = h[i];
        hb[i] = c ? atomicAdd(&gcnt[(size_t)i * GPAD], c) : 0;
        h[i] = 0;
    }
    __syncthreads();
#pragma unroll
    for (int k = 0; k < KUNR; ++k) {
        if (cr[k] >= 0) {
            int c = cr[k];
            int b = c >> 8;
            int t = hb[b] + atomicAdd(&h[b], 1);
            if (t < CAP)
                packed2[(size_t)b * CAP + t] = rr[k] | ((c & 255) << 17);
        }
    }
    for (int i = tid + KUNR * 1024; i < ne; i += 1024) { // defensive tail
        int c = col[e0 + i];
        int b = c >> 8;
        int t = hb[b] + atomicAdd(&h[b], 1);
        if (t < CAP)
            packed2[(size_t)b * CAP + t] = row[e0 + i] | ((c & 255) << 17);
    }
}

// Dense GEMM, fully coalesced: 8 threads/row (seg = lane&7), lane-adjacent
// float4 loads. W12 LOADED from global (computed by k_pre).
// Gs[node] = X@W12 + c12 (unscaled bf16, aux slots = 0, filled by k_p3).
__global__ __launch_bounds__(256) void k_gemm(const float* __restrict__ X,
                                              const float* __restrict__ W12,
                                              const float* __restrict__ c12,
                                              unsigned short* __restrict__ Gs,
                                              int n) {
    __shared__ float Wp[NF][13];   // 13-pad: seg-stride 52 -> distinct banks
    __shared__ float c12s[NC];
    int tid = threadIdx.x;
    for (int idx = tid; idx < NF * NC; idx += 256)
        Wp[idx / NC][idx % NC] = W12[idx];
    if (tid < NC) c12s[tid] = c12[tid];
    __syncthreads();

    int r = tid >> 3, seg = tid & 7;
    int gn = blockIdx.x * 32 + r;
    if (gn >= n) return;
    const float4* xb = reinterpret_cast<const float4*>(X + (size_t)gn * NF);
    float4 x0 = xb[0 * 8 + seg];
    float4 x1 = xb[1 * 8 + seg];
    float4 x2 = xb[2 * 8 + seg];
    float4 x3 = xb[3 * 8 + seg];

    float acc[NC];
#pragma unroll
    for (int c = 0; c < NC; ++c) acc[c] = 0.f;
    const float4 xs[4] = {x0, x1, x2, x3};
#pragma unroll
    for (int c = 0; c < 4; ++c) {
        float xv[4] = {xs[c].x, xs[c].y, xs[c].z, xs[c].w};
#pragma unroll
        for (int j = 0; j < 4; ++j) {
            int k = c * 32 + seg * 4 + j;
            float x = xv[j];
#pragma unroll
            for (int f = 0; f < NC; ++f) acc[f] = fmaf(x, Wp[k][f], acc[f]);
        }
    }
#pragma unroll
    for (int m = 1; m <= 4; m <<= 1) {
#pragma unroll
        for (int c = 0; c < NC; ++c) acc[c] += __shfl_xor(acc[c], m, 8);
    }
    if (seg < 2) {
        float v[NC];
#pragma unroll
        for (int c = 0; c < NC; ++c) v[c] = acc[c] + c12s[c];
        uint4* pw = (uint4*)(Gs + (size_t)gn * RW);
        if (seg == 0)
            pw[0] = make_uint4(pk_bf16(v[0], v[1]), pk_bf16(v[2], v[3]),
                               pk_bf16(v[4], 0.f), 0u);
        else
            pw[1] = make_uint4(pk_bf16(v[5], v[6]), pk_bf16(v[7], v[8]),
                               pk_bf16(v[9], 0.f), 0u);
    }
}

// P3 (r8 proven form, 512 threads): stage segment in LDS, count, scan,
// write csr IN PLACE over packed2; emits degE/offset/dis + Gs aux words.
__global__ __launch_bounds__(512) void k_p3(int* __restrict__ packed2,
                                            const int* __restrict__ gcnt,
                                            int* __restrict__ degE,
                                            int* __restrict__ offset,
                                            float* __restrict__ dis,
                                            unsigned int* __restrict__ Gu,
                                            int n, int nbuk) {
    __shared__ int cnt[256], inc[256], cnt2[256];
    __shared__ int sp[CAP];
    int b = blockIdx.x, tid = threadIdx.x;
    size_t bs = (size_t)b * CAP;
    int seg = min(gcnt[(size_t)b * GPAD], CAP);
    if (tid < 256) { cnt[tid] = 0; cnt2[tid] = 0; }
    for (int pos = tid; pos < seg; pos += 512) sp[pos] = packed2[bs + pos];
    __syncthreads();
    for (int pos = tid; pos < seg; pos += 512)
        atomicAdd(&cnt[(sp[pos] >> 17) & 255], 1);
    __syncthreads();
    if (tid < 256) inc[tid] = cnt[tid];
    __syncthreads();
    for (int s = 1; s < 256; s <<= 1) {
        int x = 0;
        if (tid < 256 && tid >= s) x = inc[tid - s];
        __syncthreads();
        if (tid < 256) inc[tid] += x;
        __syncthreads();
    }
    int node = b * 256 + tid;
    if (tid < 256 && node < n) {
        int d = cnt[tid];
        degE[node] = d;
        offset[node] = (int)bs + inc[tid] - d;
        float dv = rsqrtf((float)(d + 1));
        dis[node] = dv;
        unsigned ud = __float_as_uint(dv);
        Gu[(size_t)node * 8 + 3] = ud;   // half0 aux
        Gu[(size_t)node * 8 + 7] = ud;   // half1 aux
    }
    __syncthreads();
    for (int pos = tid; pos < seg; pos += 512) {
        int v = sp[pos];
        int l = (v >> 17) & 255;
        int t = atomicAdd(&cnt2[l], 1);
        packed2[bs + (inc[l] - cnt[l]) + t] = v & 0x1FFFF;
    }
}

// layer-1 gather: 8 lanes/node (4 nbr-groups x 2 halves), csr staged in LDS.
// FMA-scaled by each row's aux (=dis[r]); S1 = dis_c^2 * acc, aux = dis_c.
__global__ __launch_bounds__(256) void k_gather0(const unsigned short* __restrict__ Gs,
        const int* __restrict__ csr, const int* __restrict__ offset,
        const int* __restrict__ degE, const float* __restrict__ dis,
        unsigned short* __restrict__ S1, int n) {
    __shared__ int scsr[SCSR];
    int tid = threadIdx.x;
    int g0 = blockIdx.x * 32;
    int gL = min(g0 + 31, n - 1);
    int o0 = offset[g0];
    int total = offset[gL] + degE[gL] - o0;
    bool st = (total <= SCSR);
    if (st)
        for (int i = tid; i < total; i += 256) scsr[i] = csr[o0 + i];
    __syncthreads();

    int g = g0 + (tid >> 3);
    int l = tid & 7, grp = l >> 1, half = l & 1;
    if (g >= n) return;
    int o = offset[g], d = degE[g];
    int ol = o - o0;
    float dc = dis[g];
    const uint4* base = (const uint4*)Gs;
    float a0=0,a1=0,a2=0,a3=0,a4=0;
    if (grp == 0) { uint4 x = base[(size_t)g * 2 + half]; ACCF(x); }
    int j = grp;
    if (st) {
        while (j + 12 < d) {
            int r0 = scsr[ol + j], r1 = scsr[ol + j + 4];
            int r2 = scsr[ol + j + 8], r3 = scsr[ol + j + 12];
            uint4 x0 = base[(size_t)r0 * 2 + half];
            uint4 x1 = base[(size_t)r1 * 2 + half];
            uint4 x2 = base[(size_t)r2 * 2 + half];
            uint4 x3 = base[(size_t)r3 * 2 + half];
            ACCF(x0); ACCF(x1); ACCF(x2); ACCF(x3);
            j += 16;
        }
        for (; j < d; j += 4) {
            uint4 x = base[(size_t)scsr[ol + j] * 2 + half];
            ACCF(x);
        }
    } else {
        for (; j < d; j += 4) {
            uint4 x = base[(size_t)csr[o + j] * 2 + half];
            ACCF(x);
        }
    }
#pragma unroll
    for (int m = 2; m <= 4; m <<= 1) {
        a0 += __shfl_xor(a0, m, 8); a1 += __shfl_xor(a1, m, 8);
        a2 += __shfl_xor(a2, m, 8); a3 += __shfl_xor(a3, m, 8);
        a4 += __shfl_xor(a4, m, 8);
    }
    if (l < 2) {
        float s = dc * dc;
        uint4* pw = (uint4*)(S1 + (size_t)g * RW);
        pw[half] = make_uint4(pk_bf16(a0 * s, a1 * s), pk_bf16(a2 * s, a3 * s),
                              pk_bf16(a4 * s, 0.f), __float_as_uint(dc));
    }
}

// layer-2 gather + bias + fused mean-pool; csr staged in LDS. Rows pre-scaled.
__global__ __launch_bounds__(256) void k_gather_pool(const unsigned short* __restrict__ S1,
        const int* __restrict__ csr, const int* __restrict__ offset,
        const int* __restrict__ degE, const float* __restrict__ dis,
        const float* __restrict__ b2, const int* __restrict__ batch,
        float* __restrict__ psum, float* __restrict__ cnt, int n) {
    __shared__ float ps[NG * NC];
    __shared__ float lc[NG];
    __shared__ float b2s[NC];
    __shared__ int scsr[SCSR];
    int tid = threadIdx.x;
    for (int idx = tid; idx < NG * NC; idx += 256) ps[idx] = 0.f;
    if (tid < NG) lc[tid] = 0.f;
    if (tid < NC) b2s[tid] = b2[tid];

    int g0 = blockIdx.x * 32;
    int gL = min(g0 + 31, n - 1);
    int o0 = offset[g0];
    int total = offset[gL] + degE[gL] - o0;
    bool st = (total <= SCSR);
    if (st)
        for (int i = tid; i < total; i += 256) scsr[i] = csr[o0 + i];
    __syncthreads();

    int g = g0 + (tid >> 3);
    int l = tid & 7, grp = l >> 1, half = l & 1;
    if (g < n) {
        int o = offset[g], d = degE[g];
        int ol = o - o0;
        float dc = dis[g];
        const uint4* base = (const uint4*)S1;
        float a0=0,a1=0,a2=0,a3=0,a4=0, ds=0;
        if (grp == 0) { uint4 x = base[(size_t)g * 2 + half]; ACC5(x); }
        int j = grp;
        if (st) {
            while (j + 12 < d) {
                int r0 = scsr[ol + j], r1 = scsr[ol + j + 4];
                int r2 = scsr[ol + j + 8], r3 = scsr[ol + j + 12];
                uint4 x0 = base[(size_t)r0 * 2 + half];
                uint4 x1 = base[(size_t)r1 * 2 + half];
                uint4 x2 = base[(size_t)r2 * 2 + half];
                uint4 x3 = base[(size_t)r3 * 2 + half];
                ACC5(x0); ACC5(x1); ACC5(x2); ACC5(x3);
                j += 16;
            }
            for (; j < d; j += 4) {
                uint4 x = base[(size_t)scsr[ol + j] * 2 + half];
                ACC5(x);
            }
        } else {
            for (; j < d; j += 4) {
                uint4 x = base[(size_t)csr[o + j] * 2 + half];
                ACC5(x);
            }
        }
#pragma unroll
        for (int m = 2; m <= 4; m <<= 1) {
            a0 += __shfl_xor(a0, m, 8); a1 += __shfl_xor(a1, m, 8);
            a2 += __shfl_xor(a2, m, 8); a3 += __shfl_xor(a3, m, 8);
            a4 += __shfl_xor(a4, m, 8); ds += __shfl_xor(ds, m, 8);
        }
        if (l < 2) {
            float bias = dc * ds;
            int b = batch[g];
            int f0 = half * 5;
            atomicAdd(&ps[b * NC + f0 + 0], dc * a0 + bias * b2s[f0 + 0]);
            atomicAdd(&ps[b * NC + f0 + 1], dc * a1 + bias * b2s[f0 + 1]);
            atomicAdd(&ps[b * NC + f0 + 2], dc * a2 + bias * b2s[f0 + 2]);
            atomicAdd(&ps[b * NC + f0 + 3], dc * a3 + bias * b2s[f0 + 3]);
            atomicAdd(&ps[b * NC + f0 + 4], dc * a4 + bias * b2s[f0 + 4]);
            if (half == 1) atomicAdd(&lc[b], 1.0f);
        }
    }
    __syncthreads();
    for (int idx = tid; idx < NG * NC; idx += 256) {
        float v = ps[idx];
        if (v != 0.f) atomicAdd(&psum[idx], v);
    }
    if (tid < NG) {
        float v = lc[tid];
        if (v != 0.f) atomicAdd(&cnt[tid], v);
    }
}

__global__ void k_final(const float* __restrict__ psum, const float* __restrict__ cnt,
                        float* __restrict__ out) {
    int g = threadIdx.x;
    if (g < NG) {
        float cg = fmaxf(cnt[g], 1.0f);
        float l[NC];
        float m = -1e30f;
#pragma unroll
        for (int c = 0; c < NC; ++c) { l[c] = psum[g * NC + c] / cg; m = fmaxf(m, l[c]); }
        float se = 0.f;
#pragma unroll
        for (int c = 0; c < NC; ++c) se += expf(l[c] - m);
        float lse = m + logf(se);
#pragma unroll
        for (int c = 0; c < NC; ++c) out[g * NC + c] = l[c] - lse;
    }
}

extern "C" void kernel_launch(void* const* d_in, const int* in_sizes, int n_in,
                              void* d_out, int out_size, void* d_ws, size_t ws_size,
                              hipStream_t stream) {
    const float* X   = (const float*)d_in[0];
    const int* ei    = (const int*)d_in[1];
    const int* batch = (const int*)d_in[2];
    const float* W1  = (const float*)d_in[4];
    const float* b1  = (const float*)d_in[5];
    const float* W2  = (const float*)d_in[6];
    const float* b2  = (const float*)d_in[7];
    float* out = (float*)d_out;

    int n = in_sizes[0] / NF;   // 100000
    int E = in_sizes[1] / 2;    // 1600000
    const int* row = ei;
    const int* col = ei + E;

    int nbuk = cdiv(n, 256);    // 391
    int CH = cdiv(E, NBLK);     // 6250

    char* p = (char*)d_ws;
    int*   gcnt   = (int*)p;   p += (size_t)NBUKMAX * GPAD * 4;   // \ one
    float* psum   = (float*)p; p += (size_t)NG * NC * 4;          //  | zero
    float* cnt    = (float*)p; p += (size_t)NG * 4;               // / region
    int*   packed2= (int*)p;   p += (size_t)NBUKMAX * CAP * 4;    // 13.1 MB (csr in place)
    int*   degE   = (int*)p;   p += (size_t)n * 4;
    int*   offset = (int*)p;   p += (size_t)n * 4;
    float* dis    = (float*)p; p += (size_t)n * 4;
    unsigned short* Gs = (unsigned short*)p; p += (size_t)n * RW * 2;
    unsigned short* S1 = (unsigned short*)p; p += (size_t)n * RW * 2;
    float* W12    = (float*)p; p += NF * NC * 4;
    float* c12    = (float*)p; p += 16 * 4;

    const int B = 256;
    int nz = NBUKMAX * GPAD + NG * NC + NG;   // 7104 ints < 7*1024
    int preB = NZB + cdiv(NF * NC + NC, 128); // 7 + 11 = 18

    k_pre<<<preB, 1024, 0, stream>>>(gcnt, nz, W1, b1, W2, W12, c12);
    k_sort<<<NBLK, 1024, 0, stream>>>(row, col, gcnt, packed2, E, CH, nbuk);
    k_gemm<<<cdiv(n, 32), B, 0, stream>>>(X, W12, c12, Gs, n);
    k_p3<<<nbuk, 512, 0, stream>>>(packed2, gcnt, degE, offset, dis,
                                   (unsigned int*)Gs, n, nbuk);
    k_gather0<<<cdiv(n, 32), B, 0, stream>>>(Gs, packed2, offset, degE, dis, S1, n);
    k_gather_pool<<<cdiv(n, 32), B, 0, stream>>>(S1, packed2, offset, degE, dis, b2,
                                                 batch, psum, cnt, n);
    k_final<<<1, 64, 0, stream>>>(psum, cnt, out);
}